// Round 7
// baseline (5040.760 us; speedup 1.0000x reference)
//
#include <hip/hip_runtime.h>

// Seq2SeqBridge: persistent cooperative kernel, f16 MFMA, register-resident weights.
// R7 vs R6 (2970 us): 2-stream software pipelining. The two batch-groups are
// independent recurrence chains; instead of running them on disjoint WG sets
// (each idle-waiting its own sync chain), 128 WGs each interleave bg0/bg1 ticks.
// While stream A's store-ack/flag/detect propagates (~1 iteration), the WG runs
// stream B's full tick -> A's flags are pre-satisfied at its next poll.
//  - Flag stores deferred one iteration: flagged right after the sync that drains
//    the stores they guard (next iteration's first barrier).
//  - wave0 polls AHEAD for the next iteration concurrently with waves 1-2's
//    pointwise -> detect RT hidden under compute.
//  - Decoder keeps R6's L0/L1 split + h0 ring chase, per stream.
//  - Encoder: each (dir,u-slice) WG interleaves bg0/bg1 (same weights, 0 extra VGPR).
//  - Grid 256 -> 128 WGs. Flags: per-WG 256B block in OUT's dec_h region, word s
//    at +64B (R5 lifetime discipline: final dec_h/dec_c held in registers past the
//    terminal poll).
// Epoch audit (per flag word): P0=1; dec tick n -> n+2 (2..258); grid=259;
// enc l0: P=260, tick tau -> 261+tau (..516), Y0=517; l1: P=518, tick -> 519+tau
// (..774); terminal=775. Monotone per word. Chase margins as R6.

typedef _Float16 f16;
typedef _Float16 hvec8 __attribute__((ext_vector_type(8)));
typedef float fvec4 __attribute__((ext_vector_type(4)));

#define WS_H1   135168
#define WS_HE   266240
#define WS_DEC  397312
#define WS_Y0   17174528
// h0 ring: [4 slot][32 b][1024] f16 overlaid at WS_Y0 (decoder phase only)

__device__ __forceinline__ fvec4 mf(hvec8 a, hvec8 b, fvec4 c) {
    return __builtin_amdgcn_mfma_f32_16x16x32_f16(a, b, c, 0, 0, 0);
}

__device__ __forceinline__ hvec8 ldb8(const float* p) {
    hvec8 h;
#pragma unroll
    for (int j = 0; j < 8; ++j) h[j] = (f16)p[j];
    return h;
}

// cross-WG state reads: one 16B load at agent scope (sc1 -> LLC). Callers batch
// loads then vm_wait() once.
__device__ __forceinline__ hvec8 lda8(const f16* p) {
    hvec8 v;
    asm volatile("global_load_dwordx4 %0, %1, off sc1" : "=v"(v) : "v"(p));
    return v;
}
__device__ __forceinline__ void vm_wait() {
    asm volatile("s_waitcnt vmcnt(0)" ::: "memory");
    __builtin_amdgcn_sched_barrier(0);
}

__device__ __forceinline__ void st2(f16* p, float a, float b) {
    union { f16 h[2]; unsigned u; } x;
    x.h[0] = (f16)a; x.h[1] = (f16)b;
    __hip_atomic_store((unsigned*)p, x.u, __ATOMIC_RELAXED, __HIP_MEMORY_SCOPE_AGENT);
}

__device__ __forceinline__ float sigf(float x) { return 1.f / (1.f + __expf(-x)); }
__device__ __forceinline__ float thf(float x) {
    x = fminf(15.f, fmaxf(-15.f, x));
    float e = __expf(2.f * x);
    return (e - 1.f) / (e + 1.f);
}

#define RED(t, m, w, n)  red[(((t)*16 + (m))*132) + ((w)*16) + (n)]

__device__ __forceinline__ float sum8(const float* p) {
    return ((p[0] + p[16]) + (p[32] + p[48])) + ((p[64] + p[80]) + (p[96] + p[112]));
}

__global__ void __launch_bounds__(512, 1)
seq2seq_kernel(const float* __restrict__ enc_h, const float* __restrict__ enc_c,
               const float* __restrict__ emb_W,
               const float* __restrict__ dWih0, const float* __restrict__ dWhh0,
               const float* __restrict__ dbih0, const float* __restrict__ dbhh0,
               const float* __restrict__ dWih1, const float* __restrict__ dWhh1,
               const float* __restrict__ dbih1, const float* __restrict__ dbhh1,
               const float* __restrict__ eWih, const float* __restrict__ eWhh,
               const float* __restrict__ ebih, const float* __restrict__ ebhh,
               float* __restrict__ out, char* __restrict__ ws)
{
    const int tid  = threadIdx.x;
    const int wave = tid >> 6, lane = tid & 63;
    const int wg   = blockIdx.x;       // 0..127
    const int layer= wg >> 6;          // decoder layer (0: WGs 0-63, 1: 64-127)
    const int g2   = wg & 63;          // u-slice index within layer
    const int n16  = lane & 15;
    const int kq   = (lane >> 4) * 8;
    const int m    = n16;

    // flags: per-WG 256B block; stream-s word at dword offset wg*64 + s*16
    unsigned* flags  = (unsigned*)(out + 8388608);
    unsigned* myflag = flags + (size_t)wg * 64;

    f16* H1  = (f16*)(ws + WS_H1);    // [2 par][32 b][1024]
    f16* HE  = (f16*)(ws + WS_HE);    // [2 dir][2 par][32 b][512]
    f16* DEC = (f16*)(ws + WS_DEC);   // [256][32 b][1024]
    f16* Y0  = (f16*)(ws + WS_Y0);    // [256][32 b][1024]
    f16* H0R = Y0;                    // h0 ring [4][32 b][1024] (decoder only)

    __shared__ float red[64 * 132];
    __shared__ float cst[2][16][16];  // per-stream c-state
    __shared__ float bias_l[64];

    auto stflag = [&](int word, unsigned v) {
        __hip_atomic_store(myflag + word * 16, v, __ATOMIC_RELAXED, __HIP_MEMORY_SCOPE_AGENT);
    };
    auto ldflag = [&](const unsigned* p) {
        return __hip_atomic_load(p, __ATOMIC_RELAXED, __HIP_MEMORY_SCOPE_AGENT);
    };

    // ---------------- P0: decoder weight fragments (U=16) -----------------------
    const int u0 = g2 * 16;
    hvec8 bW[4][8];
    {
        const int gate = n16 >> 2, uu = n16 & 3;
        if (layer == 0) {
#pragma unroll
            for (int t = 0; t < 4; ++t) {
                const int r = gate * 1024 + u0 + t * 4 + uu;
#pragma unroll
                for (int s = 0; s < 4; ++s)
                    bW[t][s] = ldb8(dWhh0 + (size_t)r * 1024 + wave * 128 + s * 32 + kq);
            }
        } else {
#pragma unroll
            for (int t = 0; t < 4; ++t) {
                const int r = gate * 1024 + u0 + t * 4 + uu;
#pragma unroll
                for (int s = 0; s < 8; ++s) {
                    const int k1 = wave * 256 + s * 32;
                    bW[t][s] = (k1 < 1024)
                        ? ldb8(dWih1 + (size_t)r * 1024 + k1 + kq)
                        : ldb8(dWhh1 + (size_t)r * 1024 + (k1 - 1024) + kq);
                }
            }
        }
    }
    // ---------------- P0: state init (BOTH streams) + biases ---------------------
    if (tid < 128) {
        const int j = tid >> 4, mm = tid & 15;
#pragma unroll
        for (int s = 0; s < 2; ++s) {
            const int b = s * 16 + mm, u = u0 + 2 * j;
            const float* sc = enc_c + (size_t)(layer * 32 + b) * 1024 + u;
            const float* sh = enc_h + (size_t)(layer * 32 + b) * 1024 + u;
            cst[s][2 * j][mm]     = sc[0];
            cst[s][2 * j + 1][mm] = sc[1];
            if (layer == 0) st2(H0R + (size_t)(3 * 32 + b) * 1024 + u, sh[0], sh[1]);
            else            st2(H1  + (size_t)(32 + b) * 1024 + u, sh[0], sh[1]);
        }
    }
    if (tid < 64) {
        const int t = tid >> 4, nn = tid & 15;
        const int r = (nn >> 2) * 1024 + u0 + t * 4 + (nn & 3);
        if (layer == 0) {
            const float* x0 = emb_W + 512;     // emb_W[BOS=1]
            float s = dbih0[r] + dbhh0[r];
            const float* wr = dWih0 + (size_t)r * 512;
            for (int k = 0; k < 512; ++k) s += wr[k] * x0[k];
            bias_l[tid] = s;
        } else {
            bias_l[tid] = dbih1[r] + dbhh1[r];
        }
    }
    const int ownbase = layer * 64, othbase = (layer ^ 1) * 64;
    __syncthreads();                   // drains inits
    if (wave == 0) {                   // P0 bar: own domain, both words >= 1
        if (lane == 0) { stflag(0, 1u); stflag(1, 1u); }
        const unsigned* p0 = flags + (size_t)(ownbase + lane) * 64;
        for (;;) {
            unsigned a = ldflag(p0), b = ldflag(p0 + 16);
            if (__all((int)(a >= 1u && b >= 1u))) break;
            __builtin_amdgcn_s_sleep(1);
        }
    }

    // ---------------- decoder: 514 interleaved iterations ------------------------
    for (int i = 0; i < 514; ++i) {
        const int s = i & 1, n = i >> 1;
        const bool act = layer ? (n >= 1) : (n < 256);
        __syncthreads();               // joins poll-ahead; drains prev iter stores
        if (wave == 0 && lane == 0 && i > 0)
            stflag(s ^ 1, (unsigned)(((i - 1) >> 1) + 2));
        fvec4 acc[4];
#pragma unroll
        for (int t = 0; t < 4; ++t) acc[t] = 0;
        if (act) {
            hvec8 af[8];
            if (layer == 0) {
                const f16* a0 = H0R + (size_t)(((n - 1) & 3) * 32 + s * 16 + m) * 1024
                              + wave * 128 + kq;
#pragma unroll
                for (int sN = 0; sN < 4; ++sN) af[sN] = lda8(a0 + sN * 32);
                vm_wait();
#pragma unroll
                for (int sN = 0; sN < 4; ++sN)
#pragma unroll
                    for (int t = 0; t < 4; ++t) acc[t] = mf(af[sN], bW[t][sN], acc[t]);
            } else {
                const f16* b0 = H0R + (size_t)(((n - 1) & 3) * 32 + s * 16 + m) * 1024;
                const f16* b1 = H1 + (size_t)((n & 1) * 32 + s * 16 + m) * 1024;
#pragma unroll
                for (int sN = 0; sN < 8; ++sN) {
                    const int k1 = wave * 256 + sN * 32;
                    af[sN] = lda8(k1 < 1024 ? b0 + k1 + kq : b1 + (k1 - 1024) + kq);
                }
                vm_wait();
#pragma unroll
                for (int sN = 0; sN < 8; ++sN)
#pragma unroll
                    for (int t = 0; t < 4; ++t) acc[t] = mf(af[sN], bW[t][sN], acc[t]);
            }
        }
        {
            const int mg = lane >> 4;
#pragma unroll
            for (int t = 0; t < 4; ++t)
#pragma unroll
                for (int r2 = 0; r2 < 4; ++r2)
                    RED(t, mg * 4 + r2, wave, n16) = acc[t][r2];
        }
        __syncthreads();
        if (act && tid >= 64 && tid < 192) {   // pointwise: waves 1-2
            const int q = tid - 64;
            const int j = q >> 4, m2 = q & 15;
            float hh[2];
#pragma unroll
            for (int e = 0; e < 2; ++e) {
                const int uu = 2 * j + e, tt = uu >> 2, ul = uu & 3;
                const float* p = &RED(tt, m2, 0, ul);
                const float gi = sum8(p)      + bias_l[tt * 16 + ul];
                const float gf = sum8(p + 4)  + bias_l[tt * 16 + 4 + ul];
                const float gg = sum8(p + 8)  + bias_l[tt * 16 + 8 + ul];
                const float go = sum8(p + 12) + bias_l[tt * 16 + 12 + ul];
                float c = cst[s][uu][m2];
                c = sigf(gf) * c + sigf(gi) * thf(gg);
                hh[e] = sigf(go) * thf(c);
                cst[s][uu][m2] = c;
            }
            const int b = s * 16 + m2, u = u0 + 2 * j;
            if (layer == 0) {
                st2(H0R + (size_t)((n & 3) * 32 + b) * 1024 + u, hh[0], hh[1]);
            } else {
                st2(H1 + (size_t)(((n + 1) & 1) * 32 + b) * 1024 + u, hh[0], hh[1]);
                st2(DEC + ((size_t)(n - 1) * 32 + b) * 1024 + u, hh[0], hh[1]);
            }
        }
        if (wave == 0 && i + 1 < 514) {        // poll-ahead (overlaps pointwise)
            const int s2 = (i + 1) & 1, n2 = (i + 1) >> 1;
            const unsigned town = (unsigned)(n2 + 1);
            const unsigned toth = layer ? (unsigned)(n2 + 1) : (unsigned)n2;
            const unsigned* p0 = flags + (size_t)(ownbase + lane) * 64 + s2 * 16;
            const unsigned* q0 = flags + (size_t)(othbase + lane) * 64 + s2 * 16;
            for (;;) {
                unsigned a = ldflag(p0), b = ldflag(q0);
                if (__all((int)(a >= town && b >= toth))) break;
                __builtin_amdgcn_s_sleep(1);
            }
        }
    }

    // ---------------- grid barrier: DEC (both streams) visible -------------------
    __syncthreads();                   // drains iter 513 stores
    if (wave == 0) {
        if (lane == 0) { stflag(0, 259u); stflag(1, 259u); }
        const unsigned* p0 = flags + (size_t)lane * 64;
        const unsigned* p1 = p0 + (size_t)64 * 64;
        for (;;) {
            unsigned a = ldflag(p0), b = ldflag(p1);
            if (__all((int)(a >= 259u && b >= 259u))) break;
            __builtin_amdgcn_s_sleep(1);
        }
    }
    __syncthreads();
    if (wg >= 64) return;              // L1-decoder WGs done (flags never re-polled)

    // ---------------- encoder: 64 WGs, bg-streams interleaved, U=16 --------------
    const int dir = wg >> 5, ge = wg & 31;
    const int ue0 = ge * 16;
    const int dbase = dir * 32;
    float f0h0 = 0.f, f0h1 = 0.f, f0c0 = 0.f, f0c1 = 0.f;   // final payload bg0
    float f1h0 = 0.f, f1h1 = 0.f, f1c0 = 0.f, f1c1 = 0.f;   // final payload bg1
    unsigned EB = 260;
    for (int l = 0; l < 2; ++l) {
        hvec8 bE[4][6];
        {
            const int gate = n16 >> 2, uu = n16 & 3;
            const float* Wih = eWih + (size_t)(l * 2 + dir) * 2048 * 1024;
            const float* Whh = eWhh + (size_t)(l * 2 + dir) * 2048 * 512;
#pragma unroll
            for (int t = 0; t < 4; ++t) {
                const int r = gate * 512 + ue0 + t * 4 + uu;
#pragma unroll
                for (int sN = 0; sN < 6; ++sN) {
                    const int kb = wave * 192 + sN * 32;
                    bE[t][sN] = (kb < 1024)
                        ? ldb8(Wih + (size_t)r * 1024 + kb + kq)
                        : ldb8(Whh + (size_t)r * 512 + (kb - 1024) + kq);
                }
            }
        }
        if (tid < 64) {
            const int t = tid >> 4, nn = tid & 15;
            const int r = (nn >> 2) * 512 + ue0 + t * 4 + (nn & 3);
            bias_l[tid] = ebih[(size_t)(l * 2 + dir) * 2048 + r]
                        + ebhh[(size_t)(l * 2 + dir) * 2048 + r];
        }
        if (tid < 128) {
            const int j = tid >> 4, mm = tid & 15;
#pragma unroll
            for (int s = 0; s < 2; ++s) {
                cst[s][2 * j][mm] = 0.f;
                cst[s][2 * j + 1][mm] = 0.f;
                st2(HE + (size_t)((dir * 2 + 1) * 32 + s * 16 + mm) * 512 + ue0 + 2 * j,
                    0.f, 0.f);
            }
        }
        __syncthreads();               // drains inits
        if (wave == 0) {               // P-bar: dir domain, value EB
            if (lane == 0) { stflag(0, EB); stflag(1, EB); }
            const unsigned* p0 = flags + (size_t)(dbase + (lane & 31)) * 64;
            for (;;) {
                unsigned a = ldflag(p0);
                if (__all((int)(a >= EB))) break;
                __builtin_amdgcn_s_sleep(1);
            }
        }
        const f16* yprev = l ? Y0 : DEC;
        for (int j2 = 0; j2 < 512; ++j2) {
            const int s = j2 & 1, tau = j2 >> 1;
            const int t = dir ? (255 - tau) : tau;
            const int prd = (tau + 1) & 1, pwr = tau & 1;
            __syncthreads();           // joins poll-ahead; drains prev iter stores
            if (wave == 0 && lane == 0 && j2 > 0)
                stflag(s ^ 1, EB + (unsigned)(((j2 - 1) >> 1) + 1));
            const int b = s * 16 + n16;
            hvec8 af[6];
#pragma unroll
            for (int sN = 0; sN < 6; ++sN) {
                const int kb = wave * 192 + sN * 32;
                const f16* p = (kb < 1024)
                    ? yprev + ((size_t)t * 32 + b) * 1024 + kb + kq
                    : HE + (size_t)((dir * 2 + prd) * 32 + b) * 512 + (kb - 1024) + kq;
                af[sN] = lda8(p);
            }
            vm_wait();
            fvec4 acc2[4];
#pragma unroll
            for (int t2 = 0; t2 < 4; ++t2) acc2[t2] = 0;
#pragma unroll
            for (int sN = 0; sN < 6; ++sN)
#pragma unroll
                for (int t2 = 0; t2 < 4; ++t2)
                    acc2[t2] = mf(af[sN], bE[t2][sN], acc2[t2]);
            {
                const int mg = lane >> 4;
#pragma unroll
                for (int t2 = 0; t2 < 4; ++t2)
#pragma unroll
                    for (int r2 = 0; r2 < 4; ++r2)
                        RED(t2, mg * 4 + r2, wave, n16) = acc2[t2][r2];
            }
            __syncthreads();
            if (tid >= 64 && tid < 192) {      // pointwise: waves 1-2
                const int q = tid - 64;
                const int j = q >> 4, m2 = q & 15;
                float hh[2], cc[2];
#pragma unroll
                for (int e = 0; e < 2; ++e) {
                    const int uu = 2 * j + e, tt = uu >> 2, ul = uu & 3;
                    const float* p = &RED(tt, m2, 0, ul);
                    const float gi = sum8(p)      + bias_l[tt * 16 + ul];
                    const float gf = sum8(p + 4)  + bias_l[tt * 16 + 4 + ul];
                    const float gg = sum8(p + 8)  + bias_l[tt * 16 + 8 + ul];
                    const float go = sum8(p + 12) + bias_l[tt * 16 + 12 + ul];
                    float c = cst[s][uu][m2];
                    c = sigf(gf) * c + sigf(gi) * thf(gg);
                    hh[e] = sigf(go) * thf(c);
                    cc[e] = c;
                    cst[s][uu][m2] = c;
                }
                const int b2 = s * 16 + m2, u = ue0 + 2 * j;
                st2(HE + (size_t)((dir * 2 + pwr) * 32 + b2) * 512 + u, hh[0], hh[1]);
                if (l == 0) {
                    st2(Y0 + ((size_t)t * 32 + b2) * 1024 + dir * 512 + u, hh[0], hh[1]);
                } else {
                    float* o = out + ((size_t)b2 * 256 + t) * 1024 + dir * 512 + u;
                    o[0] = hh[0]; o[1] = hh[1];
                    if (tau == 255) {          // final states -> registers
                        if (s == 0) { f0h0 = hh[0]; f0h1 = hh[1]; f0c0 = cc[0]; f0c1 = cc[1]; }
                        else        { f1h0 = hh[0]; f1h1 = hh[1]; f1c0 = cc[0]; f1c1 = cc[1]; }
                    }
                }
            }
            if (wave == 0 && j2 + 1 < 512) {   // poll-ahead (overlaps pointwise)
                const int s2 = (j2 + 1) & 1, tau2 = (j2 + 1) >> 1;
                const unsigned tgt = EB + (unsigned)tau2;
                const unsigned* p0 = flags + (size_t)(dbase + (lane & 31)) * 64 + s2 * 16;
                for (;;) {
                    unsigned a = ldflag(p0);
                    if (__all((int)(a >= tgt))) break;
                    __builtin_amdgcn_s_sleep(1);
                }
            }
        }
        __syncthreads();               // drains last iteration's stores
        if (l == 0) {                  // Y0 bar (both dirs, both streams)
            if (wave == 0) {
                if (lane == 0) { stflag(0, EB + 257u); stflag(1, EB + 257u); }
                const unsigned* p0 = flags + (size_t)lane * 64;
                for (;;) {
                    unsigned a = ldflag(p0);
                    if (__all((int)(a >= EB + 257u))) break;
                    __builtin_amdgcn_s_sleep(1);
                }
            }
            __syncthreads();
            EB += 258;
        }
    }
    // terminal barrier: LAST poll anywhere; after it the flag region is dead.
    if (wave == 0) {
        if (lane == 0) { stflag(0, EB + 257u); stflag(1, EB + 257u); }
        const unsigned* p0 = flags + (size_t)lane * 64;
        for (;;) {
            unsigned a = ldflag(p0);
            if (__all((int)(a >= EB + 257u))) break;
            __builtin_amdgcn_s_sleep(1);
        }
    }
    __syncthreads();
    if (tid >= 64 && tid < 192) {      // final dec_h/dec_c writes (both streams)
        const int q = tid - 64;
        const int j = q >> 4, m2 = q & 15;
        const int col = dir * 512 + ue0 + 2 * j;
        {
            float* oh = out + 8388608 + (size_t)m2 * 1024 + col;
            float* oc = out + 8454144 + (size_t)m2 * 1024 + col;
            oh[0] = f0h0; oh[1] = f0h1; oh[32768] = f0h0; oh[32769] = f0h1;
            oc[0] = f0c0; oc[1] = f0c1; oc[32768] = f0c0; oc[32769] = f0c1;
        }
        {
            float* oh = out + 8388608 + (size_t)(16 + m2) * 1024 + col;
            float* oc = out + 8454144 + (size_t)(16 + m2) * 1024 + col;
            oh[0] = f1h0; oh[1] = f1h1; oh[32768] = f1h0; oh[32769] = f1h1;
            oc[0] = f1c0; oc[1] = f1c1; oc[32768] = f1c0; oc[32769] = f1c1;
        }
    }
}

extern "C" void kernel_launch(void* const* d_in, const int* in_sizes, int n_in,
                              void* d_out, int out_size, void* d_ws, size_t ws_size,
                              hipStream_t stream) {
    (void)in_sizes; (void)n_in; (void)out_size; (void)ws_size;
    const float* enc_h = (const float*)d_in[1];
    const float* enc_c = (const float*)d_in[2];
    const float* emb_W = (const float*)d_in[4];
    const float* dWih0 = (const float*)d_in[5];
    const float* dWhh0 = (const float*)d_in[6];
    const float* dbih0 = (const float*)d_in[7];
    const float* dbhh0 = (const float*)d_in[8];
    const float* dWih1 = (const float*)d_in[9];
    const float* dWhh1 = (const float*)d_in[10];
    const float* dbih1 = (const float*)d_in[11];
    const float* dbhh1 = (const float*)d_in[12];
    const float* eWih  = (const float*)d_in[13];
    const float* eWhh  = (const float*)d_in[14];
    const float* ebih  = (const float*)d_in[15];
    const float* ebhh  = (const float*)d_in[16];
    float* outp = (float*)d_out;
    char* ws = (char*)d_ws;

    // zero the flag region (in OUT's dec_h area; overwritten with real dec_h values
    // only after the kernel's terminal barrier)
    hipMemsetAsync((char*)d_out + 33554432, 0, 65536, stream);

    void* args[] = {&enc_h, &enc_c, &emb_W, &dWih0, &dWhh0, &dbih0, &dbhh0,
                    &dWih1, &dWhh1, &dbih1, &dbhh1, &eWih, &eWhh, &ebih, &ebhh,
                    &outp, &ws};
    hipLaunchCooperativeKernel((const void*)seq2seq_kernel, dim3(128), dim3(512),
                               args, 0, stream);
}